// Round 2
// baseline (149.905 us; speedup 1.0000x reference)
//
#include <hip/hip_runtime.h>

#define Bb 2
#define Ll 1024
#define Dd 256
#define Ee 64
#define Tt 8

typedef float f4 __attribute__((ext_vector_type(4)));

// Kernel 1: fold output projection into per-type transforms.
// M1[t][e][d] = sum_m W[e][m]     * LT[t][m][d]
// M2[t][e][d] = sum_m W[e][256+m] * RT[t][m][d]
__global__ void combine_kernel(const float* __restrict__ LT,
                               const float* __restrict__ RT,
                               const float* __restrict__ W,
                               float* __restrict__ M1,
                               float* __restrict__ M2) {
    int t = blockIdx.x >> 6;   // grid = T*E
    int e = blockIdx.x & 63;
    int d = threadIdx.x;       // 256 threads, one output column each
    __shared__ float s_w1[Dd], s_w2[Dd];
    s_w1[d] = W[e * (2 * Dd) + d];
    s_w2[d] = W[e * (2 * Dd) + Dd + d];
    __syncthreads();
    const float* lt = LT + t * Dd * Dd;
    const float* rt = RT + t * Dd * Dd;
    float a1 = 0.f, a2 = 0.f;
    #pragma unroll 8
    for (int m = 0; m < Dd; ++m) {
        a1 = fmaf(s_w1[m], lt[m * Dd + d], a1);   // coalesced over d
        a2 = fmaf(s_w2[m], rt[m * Dd + d], a2);
    }
    M1[(t * Ee + e) * Dd + d] = a1;
    M2[(t * Ee + e) * Dd + d] = a2;
}

// Kernel 2: lp[b][l][e] = sum_d M1[t][e][d] * emb[b][l][d],  t = types[b][l]
__global__ void proj_kernel(const float* __restrict__ emb,
                            const int* __restrict__ types,
                            const float* __restrict__ M1,
                            const float* __restrict__ M2,
                            float* __restrict__ lp,
                            float* __restrict__ rp) {
    int bl = blockIdx.x;       // grid = B*L
    int tid = threadIdx.x;     // 256 threads: 4 threads per e (d-split)
    __shared__ float s_e[Dd];
    s_e[tid] = emb[bl * Dd + tid];
    __syncthreads();
    int t = types[bl];
    int e = tid & 63;
    int chunk = tid >> 6;      // which quarter of d
    const float* m1 = M1 + (t * Ee + e) * Dd + chunk * 64;
    const float* m2 = M2 + (t * Ee + e) * Dd + chunk * 64;
    const float* se = s_e + chunk * 64;
    float a1 = 0.f, a2 = 0.f;
    #pragma unroll 8
    for (int d = 0; d < 64; ++d) {
        a1 = fmaf(m1[d], se[d], a1);
        a2 = fmaf(m2[d], se[d], a2);
    }
    __shared__ float r1[256], r2[256];
    r1[tid] = a1;
    r2[tid] = a2;
    __syncthreads();
    if (tid < 64) {
        lp[bl * Ee + tid] = r1[tid] + r1[tid + 64] + r1[tid + 128] + r1[tid + 192];
        rp[bl * Ee + tid] = r2[tid] + r2[tid + 64] + r2[tid + 128] + r2[tid + 192];
    }
}

// Kernel 3 (the bulk, pure store-bound):
// out[b][l][m][e] = lp[b][l][e] + rp[b][m][e] + bias[e]
__global__ void bcast_kernel(const float* __restrict__ lp,
                             const float* __restrict__ rp,
                             const float* __restrict__ bias,
                             f4* __restrict__ out) {
    int bl = blockIdx.x;        // grid = B*L, one block per (b,l)
    int b = bl >> 10;           // L = 1024
    int tid = threadIdx.x;      // 256 threads
    int e4 = tid & 15;          // E/4 = 16 float4 per (b,l,m)
    int ml = tid >> 4;          // 16 m values per pass

    __shared__ f4 s_lpb[16];
    if (tid < 16) {
        const f4* lp4 = (const f4*)(lp + bl * Ee);
        const f4* b4  = (const f4*)bias;
        s_lpb[tid] = lp4[tid] + b4[tid];
    }
    __syncthreads();

    const f4* rp4 = (const f4*)(rp + b * Ll * Ee);
    f4* o = out + (size_t)bl * (Ll * Ee / 4);
    f4 lv = s_lpb[e4];
    #pragma unroll 4
    for (int mm = 0; mm < Ll / 16; ++mm) {
        int m = mm * 16 + ml;
        f4 rv = rp4[m * 16 + e4];    // L2-resident (512 KB total)
        f4 v = lv + rv;
        // consecutive tid -> consecutive float4: fully coalesced, bypass L2
        __builtin_nontemporal_store(v, &o[m * 16 + e4]);
    }
}

extern "C" void kernel_launch(void* const* d_in, const int* in_sizes, int n_in,
                              void* d_out, int out_size, void* d_ws, size_t ws_size,
                              hipStream_t stream) {
    const float* emb   = (const float*)d_in[0];  // (B,L,D)
    const int*   types = (const int*)d_in[1];    // (B,L)
    const float* LT    = (const float*)d_in[2];  // (T,D,D)
    const float* RT    = (const float*)d_in[3];  // (T,D,D)
    const float* W     = (const float*)d_in[4];  // (E,2D)
    const float* bias  = (const float*)d_in[5];  // (E,)

    float* ws = (float*)d_ws;
    float* M1 = ws;                       // T*E*D = 131072 floats
    float* M2 = M1 + Tt * Ee * Dd;        // 131072
    float* lp = M2 + Tt * Ee * Dd;        // B*L*E = 131072
    float* rp = lp + Bb * Ll * Ee;        // 131072   (total 2 MiB)

    combine_kernel<<<Tt * Ee, 256, 0, stream>>>(LT, RT, W, M1, M2);
    proj_kernel<<<Bb * Ll, 256, 0, stream>>>(emb, types, M1, M2, lp, rp);
    bcast_kernel<<<Bb * Ll, 256, 0, stream>>>(lp, rp, bias, (f4*)d_out);
}